// Round 18
// baseline (97.798 us; speedup 1.0000x reference)
//
#include <hip/hip_runtime.h>
#include <hip/hip_bf16.h>

typedef unsigned short ushort_t;
typedef unsigned char uchar_t;
typedef __attribute__((ext_vector_type(8))) short short8;
typedef __attribute__((ext_vector_type(8))) unsigned short u16x8;
typedef __attribute__((ext_vector_type(4))) float f32x4;
typedef __attribute__((ext_vector_type(4))) int i32x4;

#define BETA 0.4f
#define EPS_C 0.05f
#define NB 8192
#define NH 1024
#define NL 2048
#define NC 5
#define VS_I8 800.0f
#define WS_I8 1200.0f
#define XS_I8 32.0f
#define G1_INV (1.0f / (XS_I8 * WS_I8))

static __device__ __forceinline__ float b2f(unsigned short u) {
    union { unsigned int i; float f; } x; x.i = ((unsigned int)u) << 16; return x.f;
}
static __device__ __forceinline__ unsigned short f2b(float f) {
    union { float f; unsigned int i; } x; x.f = f;
    unsigned int i = x.i;
    unsigned int r = (i + 0x7FFFu + ((i >> 16) & 1u)) >> 16;
    return (unsigned short)r;
}
static __device__ __forceinline__ char f2i8(float f, float s) {
    float q = rintf(f * s);
    q = fminf(127.f, fmaxf(-127.f, q));
    return (char)(int)q;
}

static __device__ __forceinline__ void gload16b(const uchar_t* g, uchar_t* l) {
    __builtin_amdgcn_global_load_lds((const __attribute__((address_space(1))) void*)g,
                                     (__attribute__((address_space(3))) void*)l, 16, 0, 0);
}

#define CFENCE() asm volatile("" ::: "memory")
#define MFMAI8(d, a, b) __builtin_amdgcn_mfma_i32_16x16x64_i8(a, b, d, 0, 0, 0)

// ---------------- x f32 -> i8 (x * 32) ----------------
__global__ __launch_bounds__(256) void cvt8_kernel(const float* __restrict__ in,
                                                   char* __restrict__ out, long n) {
    long i = ((long)blockIdx.x * 256 + threadIdx.x) * 16;
    if (i >= n) return;
    union { char b[16]; i32x4 v; } o;
#pragma unroll
    for (int q = 0; q < 4; ++q) {
        const float4 a = *(const float4*)(in + i + q * 4);
        o.b[q * 4 + 0] = f2i8(a.x, XS_I8);
        o.b[q * 4 + 1] = f2i8(a.y, XS_I8);
        o.b[q * 4 + 2] = f2i8(a.z, XS_I8);
        o.b[q * 4 + 3] = f2i8(a.w, XS_I8);
    }
    *(i32x4*)(out + i) = o.v;
}

// W1 [2048,1024] -> W1Ti8 [1024,2048] AND W1i8 [2048,1024], both i8 * 1200
__global__ __launch_bounds__(256) void trans_kernel(const float* __restrict__ W1,
                                                    char* __restrict__ W1Ti8,
                                                    char* __restrict__ W1i8) {
    __shared__ float tile[32][33];
    const int tx = threadIdx.x & 31, ty = threadIdx.x >> 5;
    const int k0 = blockIdx.x * 32, n0 = blockIdx.y * 32;
#pragma unroll
    for (int i = 0; i < 4; ++i) {
        const float v = W1[(size_t)(k0 + ty + i * 8) * NH + n0 + tx];
        tile[ty + i * 8][tx] = v;
        W1i8[(size_t)(k0 + ty + i * 8) * NH + n0 + tx] = f2i8(v, WS_I8);
    }
    __syncthreads();
#pragma unroll
    for (int i = 0; i < 4; ++i)
        W1Ti8[(size_t)(n0 + ty + i * 8) * NL + k0 + tx] = f2i8(tile[tx][ty + i * 8], WS_I8);
}

// ==== i8 GEMM, TRIPLE-buffered distance-2 prefetch + counted vmcnt(4) per tile ====
// Per tile t: vmcnt(4) [drains stage(t), issued 2 tiles ago; stage(t+1) stays in
// flight — queue never empty] -> barrier -> stage(t+2) into buf (t+2)%3 ->
// ds_read frags(t) -> 16 MFMA.  One barrier, one counted wait per tile.
// EPI 0: GEMM1  A=xi8[8192,2048] Bt=W1Ti8[1024,2048]  grid 512, tanh -> hout bf16
// EPI 1: GEMM2  A=vi8[8192,1024] Bt=W1i8 [2048,1024]  grid 1024, row |.| partials
template <int EPI>
__global__ __launch_bounds__(256, 3) void gi8(const char* __restrict__ A,
                                              const char* __restrict__ Bt,
                                              const float* __restrict__ b1,
                                              ushort_t* __restrict__ hout,
                                              float* __restrict__ partout) {
    constexpr int K  = (EPI == 0) ? 2048 : 1024;
    constexpr int NT = K / 64;                  // 32 / 16

    __shared__ uchar_t As[3][8192];             // 128 rows x 64B, pair-packed 128B lines
    __shared__ uchar_t Bs[3][8192];             // 3 bufs x (8+8)KB = 48KB

    const int tid = threadIdx.x;
    const int wv = tid >> 6, lane = tid & 63;
    const int wm = (wv >> 1) & 1, wn = wv & 1;  // wave tile 64x64
    const int fr = lane & 15, fg = lane >> 4;

    const int xcd = blockIdx.x & 7, loc = blockIdx.x >> 3;
    const int bm0 = (EPI == 0) ? (xcd * 8 + (loc >> 3)) * 128
                               : (xcd * 8 + (loc >> 4)) * 128;
    const int bnIdx = (EPI == 0) ? (loc & 7) : (loc & 15);
    const int bn0 = bnIdx * 128;

    const int t8 = tid >> 3, t7 = tid & 7;

#define STAF(BUF, KT) {                                                     \
    _Pragma("unroll") for (int j_ = 0; j_ < 2; ++j_) {                      \
        const int r1_ = j_ * 32 + t8;                                       \
        const int sl_ = (t7 * 2) ^ ((r1_ & 7) << 1);                        \
        const int row_ = 2 * r1_ + (sl_ >> 3);                              \
        const int cb_ = (KT) * 64 + (sl_ & 7) * 8;                          \
        gload16b((const uchar_t*)A + (size_t)(bm0 + row_) * K + cb_,        \
                 &As[BUF][j_ * 4096 + wv * 1024]);                          \
    } }
#define STBF(BUF, KT) {                                                     \
    _Pragma("unroll") for (int j_ = 0; j_ < 2; ++j_) {                      \
        const int r1_ = j_ * 32 + t8;                                       \
        const int sl_ = (t7 * 2) ^ ((r1_ & 7) << 1);                        \
        const int row_ = 2 * r1_ + (sl_ >> 3);                              \
        const int cb_ = (KT) * 64 + (sl_ & 7) * 8;                          \
        gload16b((const uchar_t*)Bt + (size_t)(bn0 + row_) * K + cb_,       \
                 &Bs[BUF][j_ * 4096 + wv * 1024]);                          \
    } }

    auto ldA = [&](int buf, int mf) -> i32x4 {
        const int row = wm * 64 + mf * 16 + fr;
        const int r1 = row >> 1;
        const int phys = (((row & 1) << 3) | (fg << 1)) ^ ((r1 & 7) << 1);
        return *(const i32x4*)&As[buf][r1 * 128 + phys * 8];
    };
    auto ldB = [&](int buf, int nf) -> i32x4 {
        const int row = wn * 64 + nf * 16 + fr;
        const int r1 = row >> 1;
        const int phys = (((row & 1) << 3) | (fg << 1)) ^ ((r1 & 7) << 1);
        return *(const i32x4*)&Bs[buf][r1 * 128 + phys * 8];
    };

    i32x4 acc[4][4] = {};

    // prologue: stage tiles 0 (buf0) and 1 (buf1); tile 0's vmcnt(4) drains stage(0)
    STAF(0, 0) STBF(0, 0)
    STAF(1, 1) STBF(1, 1)

#define TILEI(BUF, PRE, TT) {                                               \
    const int t_ = (TT);                                                    \
    if (t_ + 1 < NT) { asm volatile("s_waitcnt vmcnt(4)" ::: "memory"); }   \
    else             { asm volatile("s_waitcnt vmcnt(0)" ::: "memory"); }   \
    CFENCE(); __builtin_amdgcn_s_barrier(); CFENCE();                       \
    if (t_ + 2 < NT) { STAF(PRE, t_ + 2) STBF(PRE, t_ + 2) }                \
    i32x4 af[4], bf[4];                                                     \
    _Pragma("unroll") for (int n_ = 0; n_ < 4; ++n_) bf[n_] = ldB(BUF, n_); \
    _Pragma("unroll") for (int m_ = 0; m_ < 4; ++m_) af[m_] = ldA(BUF, m_); \
    __builtin_amdgcn_s_setprio(1);                                          \
    _Pragma("unroll") for (int m_ = 0; m_ < 4; ++m_)                        \
        _Pragma("unroll") for (int n_ = 0; n_ < 4; ++n_)                    \
            acc[m_][n_] = MFMAI8(acc[m_][n_], af[m_], bf[n_]);              \
    __builtin_amdgcn_s_setprio(0);                                          \
    }

    int t = 0;
#pragma unroll 1
    for (; t + 3 <= NT; t += 3) {
        TILEI(0, 2, t)
        TILEI(1, 0, t + 1)
        TILEI(2, 1, t + 2)
    }
    if (t < NT)     TILEI(0, 2, t)       // NT%3==1 tail (t%3==0)
    if (t + 1 < NT) TILEI(1, 0, t + 1)   // NT%3==2 tail
#undef TILEI
#undef STAF
#undef STBF

    if constexpr (EPI == 0) {
#pragma unroll
        for (int m = 0; m < 4; ++m)
#pragma unroll
            for (int n = 0; n < 4; ++n) {
                const int col = bn0 + wn * 64 + n * 16 + fr;
                const float bb = b1[col];
                const size_t rbase = (size_t)(bm0 + wm * 64 + m * 16 + fg * 4) * NH + col;
#pragma unroll
                for (int r = 0; r < 4; ++r)
                    hout[rbase + (size_t)r * NH] =
                        f2b(tanhf((float)acc[m][n][r] * G1_INV + bb));
            }
    } else {
        __syncthreads();
        float* rsum = (float*)&As[0][0];
#pragma unroll
        for (int m = 0; m < 4; ++m)
#pragma unroll
            for (int r = 0; r < 4; ++r) {
                float s = 0.f;
#pragma unroll
                for (int n = 0; n < 4; ++n) s += fabsf((float)acc[m][n][r]);
                s += __shfl_xor(s, 1); s += __shfl_xor(s, 2);
                s += __shfl_xor(s, 4); s += __shfl_xor(s, 8);
                if (fr == 0) rsum[wn * 128 + wm * 64 + m * 16 + fg * 4 + r] = s;
            }
        __syncthreads();
        if (tid < 128)
            partout[(size_t)bnIdx * NB + bm0 + tid] = rsum[tid] + rsum[128 + tid];
    }
}

// ---------------- per-row kernel: logits, losses, v (i8 out, scaled x800) ----------------
__global__ __launch_bounds__(256) void rows_kernel(const ushort_t* __restrict__ hb,
                                                   const int* __restrict__ y,
                                                   const float* __restrict__ W2,
                                                   const float* __restrict__ b2,
                                                   char* __restrict__ vb,
                                                   float4* __restrict__ rowstats) {
    __shared__ float w2t[NC][NH];
    __shared__ float b2s[NC];
    const int tid = threadIdx.x;
    for (int i = tid; i < NH * NC; i += 256) w2t[i % NC][i / NC] = W2[i];
    if (tid < NC) b2s[tid] = b2[tid];
    __syncthreads();
    const int wid = tid >> 6, lane = tid & 63;
    const int row = blockIdx.x * 4 + wid;
    const ushort_t* hrow = hb + (size_t)row * NH;
    char* vrow = vb + (size_t)row * NH;
    const int yi = y[row];
    float d0 = 0, d1 = 0, d2 = 0, d3 = 0, d4 = 0;
#pragma unroll
    for (int it = 0; it < 2; ++it) {
        const int n0 = it * 512 + lane * 8;
        u16x8 hv = *(const u16x8*)(hrow + n0);
        float hh[8];
#pragma unroll
        for (int j = 0; j < 8; ++j) hh[j] = b2f(hv[j]);
#pragma unroll
        for (int c = 0; c < NC; ++c) {
            const float4 a = *(const float4*)&w2t[c][n0];
            const float4 b = *(const float4*)&w2t[c][n0 + 4];
            float d = hh[0] * a.x; d += hh[1] * a.y; d += hh[2] * a.z; d += hh[3] * a.w;
            d += hh[4] * b.x; d += hh[5] * b.y; d += hh[6] * b.z; d += hh[7] * b.w;
            if (c == 0) d0 += d; else if (c == 1) d1 += d; else if (c == 2) d2 += d;
            else if (c == 3) d3 += d; else d4 += d;
        }
        const float4 ya = *(const float4*)&w2t[yi][n0];
        const float4 yb = *(const float4*)&w2t[yi][n0 + 4];
        const float yw[8] = { ya.x, ya.y, ya.z, ya.w, yb.x, yb.y, yb.z, yb.w };
        union { char b[8]; long l; } ov;
#pragma unroll
        for (int j = 0; j < 8; ++j)
            ov.b[j] = f2i8((1.f - hh[j] * hh[j]) * yw[j], VS_I8);
        *(long*)(vrow + n0) = ov.l;
    }
#pragma unroll
    for (int off = 32; off; off >>= 1) {
        d0 += __shfl_xor(d0, off); d1 += __shfl_xor(d1, off); d2 += __shfl_xor(d2, off);
        d3 += __shfl_xor(d3, off); d4 += __shfl_xor(d4, off);
    }
    if (lane == 0) {
        float lg[NC] = { d0 + b2s[0], d1 + b2s[1], d2 + b2s[2], d3 + b2s[3], d4 + b2s[4] };
        float zy = lg[yi];
        float mse = 0.f, marg = 0.f;
        int amax = 0; float best = lg[0];
#pragma unroll
        for (int c = 0; c < NC; ++c) {
            float t = lg[c] - (c == yi ? 1.f : 0.f);
            mse += t * t;
            if (c != yi) marg += fmaxf(1.f - zy + lg[c], 0.f);
            if (lg[c] > best) { best = lg[c]; amax = c; }
        }
        rowstats[row] = make_float4(zy, mse, marg, (amax == yi) ? 1.f : 0.f);
    }
}

// ---------------- reductions ----------------
__global__ __launch_bounds__(256) void reduce_rows(const float4* __restrict__ rs,
                                                   const float* __restrict__ part,
                                                   int NT, float4* __restrict__ bsums) {
    const int tid = threadIdx.x;
    const int r = blockIdx.x * 256 + tid;
    float4 v = rs[r];
    float wl1 = 0.f;
    for (int t = 0; t < NT; ++t) wl1 += part[(size_t)t * NB + r];
    wl1 *= (1.0f / (VS_I8 * WS_I8));
    float R = wl1 * EPS_C / (fabsf(v.x) + 1e-8f);
    float4 s = make_float4(v.y, v.z, v.w, log1pf(R));
#pragma unroll
    for (int off = 32; off; off >>= 1) {
        s.x += __shfl_down(s.x, off); s.y += __shfl_down(s.y, off);
        s.z += __shfl_down(s.z, off); s.w += __shfl_down(s.w, off);
    }
    __shared__ float4 red[4];
    if ((tid & 63) == 0) red[tid >> 6] = s;
    __syncthreads();
    if (tid == 0) {
        float4 t = red[0];
        for (int i = 1; i < 4; ++i) { t.x += red[i].x; t.y += red[i].y; t.z += red[i].z; t.w += red[i].w; }
        bsums[blockIdx.x] = t;
    }
}

__global__ void final_combine(const float4* __restrict__ bsums, int nb, float* __restrict__ out) {
    const int l = threadIdx.x;
    float4 s = (l < nb) ? bsums[l] : make_float4(0.f, 0.f, 0.f, 0.f);
#pragma unroll
    for (int off = 32; off; off >>= 1) {
        s.x += __shfl_down(s.x, off); s.y += __shfl_down(s.y, off);
        s.z += __shfl_down(s.z, off); s.w += __shfl_down(s.w, off);
    }
    if (l == 0) {
        const float Bf = (float)NB;
        out[0] = s.x / (Bf * (float)NC) + (s.y / Bf + BETA * s.w / Bf) * (s.z / Bf);
    }
}

extern "C" void kernel_launch(void* const* d_in, const int* in_sizes, int n_in,
                              void* d_out, int out_size, void* d_ws, size_t ws_size,
                              hipStream_t stream) {
    const float* x  = (const float*)d_in[0];
    const int*   y  = (const int*)d_in[1];
    const float* W1 = (const float*)d_in[2];
    const float* b1 = (const float*)d_in[3];
    const float* W2 = (const float*)d_in[4];
    const float* b2 = (const float*)d_in[5];
    float* out = (float*)d_out;

    char* ws = (char*)d_ws;
    char*     W1Ti8 = (char*)(ws);                              // 2MB
    char*     W1i8  = (char*)(ws + (4ul << 20));                // 2MB
    char*     xi8   = (char*)(ws + (8ul << 20));                // 16MB
    ushort_t* hb    = (ushort_t*)(ws + (40ul << 20));           // 16MB
    char*     vi8   = (char*)(ws + (56ul << 20));               // 8MB
    float4*   rowstats = (float4*)(ws + (72ul << 20));          // 128KB
    float*    part = (float*)(ws + (72ul << 20) + (1ul << 20)); // 512KB
    float4*   bsums = (float4*)(ws + (74ul << 20));             // 512B

    // 1. conversions: x -> i8(x*32); W1 -> i8 both orientations
    cvt8_kernel<<<(NB * (long)NL) / (256 * 16), 256, 0, stream>>>(x, xi8, (long)NB * NL);
    trans_kernel<<<dim3(NL / 32, NH / 32), 256, 0, stream>>>(W1, W1Ti8, W1i8);

    // 2. GEMM1 (i8, 3-buf distance-2 counted vmcnt): h = tanh(x @ W1 + b1)
    gi8<0><<<512, 256, 0, stream>>>(xi8, W1Ti8, b1, hb, nullptr);

    // 3. per-row: logits/mse/margin/zy/correct + v (i8, x800)
    rows_kernel<<<NB / 4, 256, 0, stream>>>(hb, y, W2, b2, vi8, rowstats);

    // 4. GEMM2 (i8, 3-buf distance-2 counted vmcnt): g = v @ W1^T, row |.| partials
    gi8<1><<<1024, 256, 0, stream>>>(vi8, W1i8, nullptr, nullptr, part);

    // 5. reductions
    reduce_rows<<<NB / 256, 256, 0, stream>>>(rowstats, part, NL / 128, bsums);
    final_combine<<<1, 64, 0, stream>>>(bsums, NB / 256, out);
}

// Round 19
// 94.205 us; speedup vs baseline: 1.0381x; 1.0381x over previous
//
#include <hip/hip_runtime.h>
#include <hip/hip_bf16.h>

typedef unsigned short ushort_t;
typedef unsigned char uchar_t;
typedef __attribute__((ext_vector_type(8))) short short8;
typedef __attribute__((ext_vector_type(8))) unsigned short u16x8;
typedef __attribute__((ext_vector_type(4))) float f32x4;
typedef __attribute__((ext_vector_type(4))) int i32x4;

#define BETA 0.4f
#define EPS_C 0.05f
#define NB 8192
#define NH 1024
#define NL 2048
#define NC 5
#define VS_I8 800.0f
#define WS_I8 1200.0f
#define XS_I8 32.0f
#define G1_INV (1.0f / (XS_I8 * WS_I8))

static __device__ __forceinline__ float b2f(unsigned short u) {
    union { unsigned int i; float f; } x; x.i = ((unsigned int)u) << 16; return x.f;
}
static __device__ __forceinline__ unsigned short f2b(float f) {
    union { float f; unsigned int i; } x; x.f = f;
    unsigned int i = x.i;
    unsigned int r = (i + 0x7FFFu + ((i >> 16) & 1u)) >> 16;
    return (unsigned short)r;
}
static __device__ __forceinline__ char f2i8(float f, float s) {
    float q = rintf(f * s);
    q = fminf(127.f, fmaxf(-127.f, q));
    return (char)(int)q;
}

static __device__ __forceinline__ void gload16b(const uchar_t* g, uchar_t* l) {
    __builtin_amdgcn_global_load_lds((const __attribute__((address_space(1))) void*)g,
                                     (__attribute__((address_space(3))) void*)l, 16, 0, 0);
}

#define CFENCE() asm volatile("" ::: "memory")
#define MFMAI8(d, a, b) __builtin_amdgcn_mfma_i32_16x16x64_i8(a, b, d, 0, 0, 0)

// ---------------- x f32 -> i8 (x * 32) ----------------
__global__ __launch_bounds__(256) void cvt8_kernel(const float* __restrict__ in,
                                                   char* __restrict__ out, long n) {
    long i = ((long)blockIdx.x * 256 + threadIdx.x) * 16;
    if (i >= n) return;
    union { char b[16]; i32x4 v; } o;
#pragma unroll
    for (int q = 0; q < 4; ++q) {
        const float4 a = *(const float4*)(in + i + q * 4);
        o.b[q * 4 + 0] = f2i8(a.x, XS_I8);
        o.b[q * 4 + 1] = f2i8(a.y, XS_I8);
        o.b[q * 4 + 2] = f2i8(a.z, XS_I8);
        o.b[q * 4 + 3] = f2i8(a.w, XS_I8);
    }
    *(i32x4*)(out + i) = o.v;
}

// W1 [2048,1024] -> W1Ti8 [1024,2048] AND W1i8 [2048,1024], both i8 * 1200
__global__ __launch_bounds__(256) void trans_kernel(const float* __restrict__ W1,
                                                    char* __restrict__ W1Ti8,
                                                    char* __restrict__ W1i8) {
    __shared__ float tile[32][33];
    const int tx = threadIdx.x & 31, ty = threadIdx.x >> 5;
    const int k0 = blockIdx.x * 32, n0 = blockIdx.y * 32;
#pragma unroll
    for (int i = 0; i < 4; ++i) {
        const float v = W1[(size_t)(k0 + ty + i * 8) * NH + n0 + tx];
        tile[ty + i * 8][tx] = v;
        W1i8[(size_t)(k0 + ty + i * 8) * NH + n0 + tx] = f2i8(v, WS_I8);
    }
    __syncthreads();
#pragma unroll
    for (int i = 0; i < 4; ++i)
        W1Ti8[(size_t)(n0 + ty + i * 8) * NL + k0 + tx] = f2i8(tile[tx][ty + i * 8], WS_I8);
}

// ============ i8 GEMM template (r16 measured-best config, bit-exact revert) ============
// EPI 0: GEMM1  A=xi8[8192,2048] Bt=W1Ti8[1024,2048]  grid 512, tanh -> hout bf16
// EPI 1: GEMM2  A=vi8[8192,1024] Bt=W1i8 [2048,1024]  grid 1024, row |.| partials
template <int EPI>
__global__ __launch_bounds__(256, 4) void gi8(const char* __restrict__ A,
                                              const char* __restrict__ Bt,
                                              const float* __restrict__ b1,
                                              ushort_t* __restrict__ hout,
                                              float* __restrict__ partout) {
    constexpr int K  = (EPI == 0) ? 2048 : 1024;
    constexpr int NT = K / 64;                  // 32 / 16

    __shared__ uchar_t As[2][8192];             // 128 rows x 64B, pair-packed 128B lines
    __shared__ uchar_t Bs[2][8192];

    const int tid = threadIdx.x;
    const int wv = tid >> 6, lane = tid & 63;
    const int wm = (wv >> 1) & 1, wn = wv & 1;  // wave tile 64x64
    const int fr = lane & 15, fg = lane >> 4;

    const int xcd = blockIdx.x & 7, loc = blockIdx.x >> 3;
    const int bm0 = (EPI == 0) ? (xcd * 8 + (loc >> 3)) * 128
                               : (xcd * 8 + (loc >> 4)) * 128;
    const int bnIdx = (EPI == 0) ? (loc & 7) : (loc & 15);
    const int bn0 = bnIdx * 128;

    const int t8 = tid >> 3, t7 = tid & 7;

#define STAF(BUF, KT) {                                                     \
    _Pragma("unroll") for (int j_ = 0; j_ < 2; ++j_) {                      \
        const int r1_ = j_ * 32 + t8;                                       \
        const int sl_ = (t7 * 2) ^ ((r1_ & 7) << 1);                        \
        const int row_ = 2 * r1_ + (sl_ >> 3);                              \
        const int cb_ = (KT) * 64 + (sl_ & 7) * 8;                          \
        gload16b((const uchar_t*)A + (size_t)(bm0 + row_) * K + cb_,        \
                 &As[BUF][j_ * 4096 + wv * 1024]);                          \
    } }
#define STBF(BUF, KT) {                                                     \
    _Pragma("unroll") for (int j_ = 0; j_ < 2; ++j_) {                      \
        const int r1_ = j_ * 32 + t8;                                       \
        const int sl_ = (t7 * 2) ^ ((r1_ & 7) << 1);                        \
        const int row_ = 2 * r1_ + (sl_ >> 3);                              \
        const int cb_ = (KT) * 64 + (sl_ & 7) * 8;                          \
        gload16b((const uchar_t*)Bt + (size_t)(bn0 + row_) * K + cb_,       \
                 &Bs[BUF][j_ * 4096 + wv * 1024]);                          \
    } }

    auto ldA = [&](int buf, int mf) -> i32x4 {
        const int row = wm * 64 + mf * 16 + fr;
        const int r1 = row >> 1;
        const int phys = (((row & 1) << 3) | (fg << 1)) ^ ((r1 & 7) << 1);
        return *(const i32x4*)&As[buf][r1 * 128 + phys * 8];
    };
    auto ldB = [&](int buf, int nf) -> i32x4 {
        const int row = wn * 64 + nf * 16 + fr;
        const int r1 = row >> 1;
        const int phys = (((row & 1) << 3) | (fg << 1)) ^ ((r1 & 7) << 1);
        return *(const i32x4*)&Bs[buf][r1 * 128 + phys * 8];
    };

    i32x4 acc[4][4] = {};

    STAF(0, 0) STBF(0, 0)
    asm volatile("s_waitcnt vmcnt(0)" ::: "memory");
    CFENCE(); __builtin_amdgcn_s_barrier(); CFENCE();

#define TILEI(BUF, TT) {                                                    \
    const int t_ = (TT);                                                    \
    i32x4 af[4], bf[4];                                                     \
    _Pragma("unroll") for (int n_ = 0; n_ < 4; ++n_) bf[n_] = ldB(BUF, n_); \
    _Pragma("unroll") for (int m_ = 0; m_ < 4; ++m_) af[m_] = ldA(BUF, m_); \
    if (t_ + 1 < NT) { STAF(BUF ^ 1, t_ + 1) STBF(BUF ^ 1, t_ + 1) }        \
    CFENCE(); __builtin_amdgcn_s_barrier(); CFENCE();                       \
    __builtin_amdgcn_s_setprio(1);                                          \
    _Pragma("unroll") for (int m_ = 0; m_ < 4; ++m_)                        \
        _Pragma("unroll") for (int n_ = 0; n_ < 4; ++n_)                    \
            acc[m_][n_] = MFMAI8(acc[m_][n_], af[m_], bf[n_]);              \
    __builtin_amdgcn_s_setprio(0);                                          \
    asm volatile("s_waitcnt vmcnt(0)" ::: "memory");                        \
    CFENCE(); __builtin_amdgcn_s_barrier(); CFENCE();                       \
    }

#pragma unroll 1
    for (int t = 0; t < NT; t += 2) {
        TILEI(0, t)
        TILEI(1, t + 1)
    }
#undef TILEI
#undef STAF
#undef STBF

    if constexpr (EPI == 0) {
#pragma unroll
        for (int m = 0; m < 4; ++m)
#pragma unroll
            for (int n = 0; n < 4; ++n) {
                const int col = bn0 + wn * 64 + n * 16 + fr;
                const float bb = b1[col];
                const size_t rbase = (size_t)(bm0 + wm * 64 + m * 16 + fg * 4) * NH + col;
#pragma unroll
                for (int r = 0; r < 4; ++r)
                    hout[rbase + (size_t)r * NH] =
                        f2b(tanhf((float)acc[m][n][r] * G1_INV + bb));
            }
    } else {
        __syncthreads();
        float* rsum = (float*)&As[0][0];
#pragma unroll
        for (int m = 0; m < 4; ++m)
#pragma unroll
            for (int r = 0; r < 4; ++r) {
                float s = 0.f;
#pragma unroll
                for (int n = 0; n < 4; ++n) s += fabsf((float)acc[m][n][r]);
                s += __shfl_xor(s, 1); s += __shfl_xor(s, 2);
                s += __shfl_xor(s, 4); s += __shfl_xor(s, 8);
                if (fr == 0) rsum[wn * 128 + wm * 64 + m * 16 + fg * 4 + r] = s;
            }
        __syncthreads();
        if (tid < 128)
            partout[(size_t)bnIdx * NB + bm0 + tid] = rsum[tid] + rsum[128 + tid];
    }
}

// ---- per-row kernel: logits/losses/v; W2 via coalesced per-lane GLOBAL loads ----
// (old version read w2t[c][lane*8] from LDS: 32B lane stride = same-bank 8-16-way
//  conflict on every b128. Each lane needs exactly W2[n0*5 .. n0*5+40): 10 coalesced
//  float4 loads, L2-resident. yi-select via compile-time-indexed cndmask chain.)
__global__ __launch_bounds__(256) void rows_kernel(const ushort_t* __restrict__ hb,
                                                   const int* __restrict__ y,
                                                   const float* __restrict__ W2,
                                                   const float* __restrict__ b2,
                                                   char* __restrict__ vb,
                                                   float4* __restrict__ rowstats) {
    const int tid = threadIdx.x;
    const int wid = tid >> 6, lane = tid & 63;
    const int row = blockIdx.x * 4 + wid;
    const ushort_t* hrow = hb + (size_t)row * NH;
    char* vrow = vb + (size_t)row * NH;
    const int yi = y[row];
    float d0 = 0, d1 = 0, d2 = 0, d3 = 0, d4 = 0;
#pragma unroll
    for (int it = 0; it < 2; ++it) {
        const int n0 = it * 512 + lane * 8;
        u16x8 hv = *(const u16x8*)(hrow + n0);
        float hh[8];
#pragma unroll
        for (int j = 0; j < 8; ++j) hh[j] = b2f(hv[j]);
        // 40 consecutive floats: W2[(n0+j)*5 + c] for j 0..7, c 0..4
        float4 wv[10];
#pragma unroll
        for (int q = 0; q < 10; ++q)
            wv[q] = *(const float4*)(W2 + (size_t)n0 * 5 + q * 4);
        const float* wf = (const float*)&wv[0];
        union { char b[8]; long l; } ov;
#pragma unroll
        for (int j = 0; j < 8; ++j) {
            d0 += hh[j] * wf[j * 5 + 0];
            d1 += hh[j] * wf[j * 5 + 1];
            d2 += hh[j] * wf[j * 5 + 2];
            d3 += hh[j] * wf[j * 5 + 3];
            d4 += hh[j] * wf[j * 5 + 4];
            float wy = wf[j * 5 + 0];
            wy = (yi == 1) ? wf[j * 5 + 1] : wy;
            wy = (yi == 2) ? wf[j * 5 + 2] : wy;
            wy = (yi == 3) ? wf[j * 5 + 3] : wy;
            wy = (yi == 4) ? wf[j * 5 + 4] : wy;
            ov.b[j] = f2i8((1.f - hh[j] * hh[j]) * wy, VS_I8);
        }
        *(long*)(vrow + n0) = ov.l;
    }
#pragma unroll
    for (int off = 32; off; off >>= 1) {
        d0 += __shfl_xor(d0, off); d1 += __shfl_xor(d1, off); d2 += __shfl_xor(d2, off);
        d3 += __shfl_xor(d3, off); d4 += __shfl_xor(d4, off);
    }
    if (lane == 0) {
        float lg[NC] = { d0 + b2[0], d1 + b2[1], d2 + b2[2], d3 + b2[3], d4 + b2[4] };
        float zy = lg[yi];
        float mse = 0.f, marg = 0.f;
        int amax = 0; float best = lg[0];
#pragma unroll
        for (int c = 0; c < NC; ++c) {
            float t = lg[c] - (c == yi ? 1.f : 0.f);
            mse += t * t;
            if (c != yi) marg += fmaxf(1.f - zy + lg[c], 0.f);
            if (lg[c] > best) { best = lg[c]; amax = c; }
        }
        rowstats[row] = make_float4(zy, mse, marg, (amax == yi) ? 1.f : 0.f);
    }
}

// ---------------- reductions ----------------
__global__ __launch_bounds__(256) void reduce_rows(const float4* __restrict__ rs,
                                                   const float* __restrict__ part,
                                                   int NT, float4* __restrict__ bsums) {
    const int tid = threadIdx.x;
    const int r = blockIdx.x * 256 + tid;
    float4 v = rs[r];
    float wl1 = 0.f;
    for (int t = 0; t < NT; ++t) wl1 += part[(size_t)t * NB + r];
    wl1 *= (1.0f / (VS_I8 * WS_I8));
    float R = wl1 * EPS_C / (fabsf(v.x) + 1e-8f);
    float4 s = make_float4(v.y, v.z, v.w, log1pf(R));
#pragma unroll
    for (int off = 32; off; off >>= 1) {
        s.x += __shfl_down(s.x, off); s.y += __shfl_down(s.y, off);
        s.z += __shfl_down(s.z, off); s.w += __shfl_down(s.w, off);
    }
    __shared__ float4 red[4];
    if ((tid & 63) == 0) red[tid >> 6] = s;
    __syncthreads();
    if (tid == 0) {
        float4 t = red[0];
        for (int i = 1; i < 4; ++i) { t.x += red[i].x; t.y += red[i].y; t.z += red[i].z; t.w += red[i].w; }
        bsums[blockIdx.x] = t;
    }
}

__global__ void final_combine(const float4* __restrict__ bsums, int nb, float* __restrict__ out) {
    const int l = threadIdx.x;
    float4 s = (l < nb) ? bsums[l] : make_float4(0.f, 0.f, 0.f, 0.f);
#pragma unroll
    for (int off = 32; off; off >>= 1) {
        s.x += __shfl_down(s.x, off); s.y += __shfl_down(s.y, off);
        s.z += __shfl_down(s.z, off); s.w += __shfl_down(s.w, off);
    }
    if (l == 0) {
        const float Bf = (float)NB;
        out[0] = s.x / (Bf * (float)NC) + (s.y / Bf + BETA * s.w / Bf) * (s.z / Bf);
    }
}

extern "C" void kernel_launch(void* const* d_in, const int* in_sizes, int n_in,
                              void* d_out, int out_size, void* d_ws, size_t ws_size,
                              hipStream_t stream) {
    const float* x  = (const float*)d_in[0];
    const int*   y  = (const int*)d_in[1];
    const float* W1 = (const float*)d_in[2];
    const float* b1 = (const float*)d_in[3];
    const float* W2 = (const float*)d_in[4];
    const float* b2 = (const float*)d_in[5];
    float* out = (float*)d_out;

    char* ws = (char*)d_ws;
    char*     W1Ti8 = (char*)(ws);                              // 2MB
    char*     W1i8  = (char*)(ws + (4ul << 20));                // 2MB
    char*     xi8   = (char*)(ws + (8ul << 20));                // 16MB
    ushort_t* hb    = (ushort_t*)(ws + (40ul << 20));           // 16MB
    char*     vi8   = (char*)(ws + (56ul << 20));               // 8MB
    float4*   rowstats = (float4*)(ws + (72ul << 20));          // 128KB
    float*    part = (float*)(ws + (72ul << 20) + (1ul << 20)); // 512KB
    float4*   bsums = (float4*)(ws + (74ul << 20));             // 512B

    // 1. conversions: x -> i8(x*32); W1 -> i8 both orientations
    cvt8_kernel<<<(NB * (long)NL) / (256 * 16), 256, 0, stream>>>(x, xi8, (long)NB * NL);
    trans_kernel<<<dim3(NL / 32, NH / 32), 256, 0, stream>>>(W1, W1Ti8, W1i8);

    // 2. GEMM1 (i8, r16 proven): h = tanh(x @ W1 + b1)
    gi8<0><<<512, 256, 0, stream>>>(xi8, W1Ti8, b1, hb, nullptr);

    // 3. per-row: logits/mse/margin/zy/correct + v (i8, x800; conflict-free W2 path)
    rows_kernel<<<NB / 4, 256, 0, stream>>>(hb, y, W2, b2, vi8, rowstats);

    // 4. GEMM2 (i8, r16 proven): g = v @ W1^T, row |.| partials
    gi8<1><<<1024, 256, 0, stream>>>(vi8, W1i8, nullptr, nullptr, part);

    // 5. reductions
    reduce_rows<<<NB / 256, 256, 0, stream>>>(rowstats, part, NL / 128, bsums);
    final_combine<<<1, 64, 0, stream>>>(bsums, NB / 256, out);
}

// Round 20
// 91.058 us; speedup vs baseline: 1.0740x; 1.0346x over previous
//
#include <hip/hip_runtime.h>
#include <hip/hip_bf16.h>

typedef unsigned short ushort_t;
typedef unsigned char uchar_t;
typedef __attribute__((ext_vector_type(8))) short short8;
typedef __attribute__((ext_vector_type(8))) unsigned short u16x8;
typedef __attribute__((ext_vector_type(4))) float f32x4;
typedef __attribute__((ext_vector_type(4))) int i32x4;

#define BETA 0.4f
#define EPS_C 0.05f
#define NB 8192
#define NH 1024
#define NL 2048
#define NC 5
#define VS_I8 800.0f
#define WS_I8 1200.0f
#define XS_I8 32.0f
#define G1_INV (1.0f / (XS_I8 * WS_I8))
#define CVT_BLOCKS 4096   // (NB*NL)/(256*16)
#define TRANS_BLOCKS 2048 // (NL/32)*(NH/32)

static __device__ __forceinline__ float b2f(unsigned short u) {
    union { unsigned int i; float f; } x; x.i = ((unsigned int)u) << 16; return x.f;
}
static __device__ __forceinline__ unsigned short f2b(float f) {
    union { float f; unsigned int i; } x; x.f = f;
    unsigned int i = x.i;
    unsigned int r = (i + 0x7FFFu + ((i >> 16) & 1u)) >> 16;
    return (unsigned short)r;
}
static __device__ __forceinline__ char f2i8(float f, float s) {
    float q = rintf(f * s);
    q = fminf(127.f, fmaxf(-127.f, q));
    return (char)(int)q;
}

static __device__ __forceinline__ void gload16b(const uchar_t* g, uchar_t* l) {
    __builtin_amdgcn_global_load_lds((const __attribute__((address_space(1))) void*)g,
                                     (__attribute__((address_space(3))) void*)l, 16, 0, 0);
}

#define CFENCE() asm volatile("" ::: "memory")
#define MFMAI8(d, a, b) __builtin_amdgcn_mfma_i32_16x16x64_i8(a, b, d, 0, 0, 0)

// ---- merged prep: x f32 -> i8(x*32)  AND  W1 -> i8 both orientations (one dispatch) ----
__global__ __launch_bounds__(256) void prep_kernel(const float* __restrict__ x,
                                                   char* __restrict__ xi8,
                                                   const float* __restrict__ W1,
                                                   char* __restrict__ W1Ti8,
                                                   char* __restrict__ W1i8) {
    __shared__ float tile[32][33];
    if (blockIdx.x < CVT_BLOCKS) {
        const long i = ((long)blockIdx.x * 256 + threadIdx.x) * 16;
        union { char b[16]; i32x4 v; } o;
#pragma unroll
        for (int q = 0; q < 4; ++q) {
            const float4 a = *(const float4*)(x + i + q * 4);
            o.b[q * 4 + 0] = f2i8(a.x, XS_I8);
            o.b[q * 4 + 1] = f2i8(a.y, XS_I8);
            o.b[q * 4 + 2] = f2i8(a.z, XS_I8);
            o.b[q * 4 + 3] = f2i8(a.w, XS_I8);
        }
        *(i32x4*)(xi8 + i) = o.v;
    } else {
        const int b = blockIdx.x - CVT_BLOCKS;
        const int k0 = (b & 63) * 32, n0 = (b >> 6) * 32;
        const int tx = threadIdx.x & 31, ty = threadIdx.x >> 5;
#pragma unroll
        for (int i = 0; i < 4; ++i) {
            const float v = W1[(size_t)(k0 + ty + i * 8) * NH + n0 + tx];
            tile[ty + i * 8][tx] = v;
            W1i8[(size_t)(k0 + ty + i * 8) * NH + n0 + tx] = f2i8(v, WS_I8);
        }
        __syncthreads();
#pragma unroll
        for (int i = 0; i < 4; ++i)
            W1Ti8[(size_t)(n0 + ty + i * 8) * NL + k0 + tx] =
                f2i8(tile[tx][ty + i * 8], WS_I8);
    }
}

// ============ i8 GEMM template (r16 measured-best config, bit-exact) ============
// EPI 0: GEMM1  A=xi8[8192,2048] Bt=W1Ti8[1024,2048]  grid 512, tanh -> hout bf16
// EPI 1: GEMM2  A=vi8[8192,1024] Bt=W1i8 [2048,1024]  grid 1024, row |.| partials
template <int EPI>
__global__ __launch_bounds__(256, 4) void gi8(const char* __restrict__ A,
                                              const char* __restrict__ Bt,
                                              const float* __restrict__ b1,
                                              ushort_t* __restrict__ hout,
                                              float* __restrict__ partout) {
    constexpr int K  = (EPI == 0) ? 2048 : 1024;
    constexpr int NT = K / 64;                  // 32 / 16

    __shared__ uchar_t As[2][8192];             // 128 rows x 64B, pair-packed 128B lines
    __shared__ uchar_t Bs[2][8192];

    const int tid = threadIdx.x;
    const int wv = tid >> 6, lane = tid & 63;
    const int wm = (wv >> 1) & 1, wn = wv & 1;  // wave tile 64x64
    const int fr = lane & 15, fg = lane >> 4;

    const int xcd = blockIdx.x & 7, loc = blockIdx.x >> 3;
    const int bm0 = (EPI == 0) ? (xcd * 8 + (loc >> 3)) * 128
                               : (xcd * 8 + (loc >> 4)) * 128;
    const int bnIdx = (EPI == 0) ? (loc & 7) : (loc & 15);
    const int bn0 = bnIdx * 128;

    const int t8 = tid >> 3, t7 = tid & 7;

#define STAF(BUF, KT) {                                                     \
    _Pragma("unroll") for (int j_ = 0; j_ < 2; ++j_) {                      \
        const int r1_ = j_ * 32 + t8;                                       \
        const int sl_ = (t7 * 2) ^ ((r1_ & 7) << 1);                        \
        const int row_ = 2 * r1_ + (sl_ >> 3);                              \
        const int cb_ = (KT) * 64 + (sl_ & 7) * 8;                          \
        gload16b((const uchar_t*)A + (size_t)(bm0 + row_) * K + cb_,        \
                 &As[BUF][j_ * 4096 + wv * 1024]);                          \
    } }
#define STBF(BUF, KT) {                                                     \
    _Pragma("unroll") for (int j_ = 0; j_ < 2; ++j_) {                      \
        const int r1_ = j_ * 32 + t8;                                       \
        const int sl_ = (t7 * 2) ^ ((r1_ & 7) << 1);                        \
        const int row_ = 2 * r1_ + (sl_ >> 3);                              \
        const int cb_ = (KT) * 64 + (sl_ & 7) * 8;                          \
        gload16b((const uchar_t*)Bt + (size_t)(bn0 + row_) * K + cb_,       \
                 &Bs[BUF][j_ * 4096 + wv * 1024]);                          \
    } }

    auto ldA = [&](int buf, int mf) -> i32x4 {
        const int row = wm * 64 + mf * 16 + fr;
        const int r1 = row >> 1;
        const int phys = (((row & 1) << 3) | (fg << 1)) ^ ((r1 & 7) << 1);
        return *(const i32x4*)&As[buf][r1 * 128 + phys * 8];
    };
    auto ldB = [&](int buf, int nf) -> i32x4 {
        const int row = wn * 64 + nf * 16 + fr;
        const int r1 = row >> 1;
        const int phys = (((row & 1) << 3) | (fg << 1)) ^ ((r1 & 7) << 1);
        return *(const i32x4*)&Bs[buf][r1 * 128 + phys * 8];
    };

    i32x4 acc[4][4] = {};

    STAF(0, 0) STBF(0, 0)
    asm volatile("s_waitcnt vmcnt(0)" ::: "memory");
    CFENCE(); __builtin_amdgcn_s_barrier(); CFENCE();

#define TILEI(BUF, TT) {                                                    \
    const int t_ = (TT);                                                    \
    i32x4 af[4], bf[4];                                                     \
    _Pragma("unroll") for (int n_ = 0; n_ < 4; ++n_) bf[n_] = ldB(BUF, n_); \
    _Pragma("unroll") for (int m_ = 0; m_ < 4; ++m_) af[m_] = ldA(BUF, m_); \
    if (t_ + 1 < NT) { STAF(BUF ^ 1, t_ + 1) STBF(BUF ^ 1, t_ + 1) }        \
    CFENCE(); __builtin_amdgcn_s_barrier(); CFENCE();                       \
    __builtin_amdgcn_s_setprio(1);                                          \
    _Pragma("unroll") for (int m_ = 0; m_ < 4; ++m_)                        \
        _Pragma("unroll") for (int n_ = 0; n_ < 4; ++n_)                    \
            acc[m_][n_] = MFMAI8(acc[m_][n_], af[m_], bf[n_]);              \
    __builtin_amdgcn_s_setprio(0);                                          \
    asm volatile("s_waitcnt vmcnt(0)" ::: "memory");                        \
    CFENCE(); __builtin_amdgcn_s_barrier(); CFENCE();                       \
    }

#pragma unroll 1
    for (int t = 0; t < NT; t += 2) {
        TILEI(0, t)
        TILEI(1, t + 1)
    }
#undef TILEI
#undef STAF
#undef STBF

    if constexpr (EPI == 0) {
#pragma unroll
        for (int m = 0; m < 4; ++m)
#pragma unroll
            for (int n = 0; n < 4; ++n) {
                const int col = bn0 + wn * 64 + n * 16 + fr;
                const float bb = b1[col];
                const size_t rbase = (size_t)(bm0 + wm * 64 + m * 16 + fg * 4) * NH + col;
#pragma unroll
                for (int r = 0; r < 4; ++r)
                    hout[rbase + (size_t)r * NH] =
                        f2b(tanhf((float)acc[m][n][r] * G1_INV + bb));
            }
    } else {
        __syncthreads();
        float* rsum = (float*)&As[0][0];
#pragma unroll
        for (int m = 0; m < 4; ++m)
#pragma unroll
            for (int r = 0; r < 4; ++r) {
                float s = 0.f;
#pragma unroll
                for (int n = 0; n < 4; ++n) s += fabsf((float)acc[m][n][r]);
                s += __shfl_xor(s, 1); s += __shfl_xor(s, 2);
                s += __shfl_xor(s, 4); s += __shfl_xor(s, 8);
                if (fr == 0) rsum[wn * 128 + wm * 64 + m * 16 + fg * 4 + r] = s;
            }
        __syncthreads();
        if (tid < 128)
            partout[(size_t)bnIdx * NB + bm0 + tid] = rsum[tid] + rsum[128 + tid];
    }
}

// ---------------- per-row kernel (r16 measured-best version) ----------------
__global__ __launch_bounds__(256) void rows_kernel(const ushort_t* __restrict__ hb,
                                                   const int* __restrict__ y,
                                                   const float* __restrict__ W2,
                                                   const float* __restrict__ b2,
                                                   char* __restrict__ vb,
                                                   float4* __restrict__ rowstats) {
    __shared__ float w2t[NC][NH];
    __shared__ float b2s[NC];
    const int tid = threadIdx.x;
    for (int i = tid; i < NH * NC; i += 256) w2t[i % NC][i / NC] = W2[i];
    if (tid < NC) b2s[tid] = b2[tid];
    __syncthreads();
    const int wid = tid >> 6, lane = tid & 63;
    const int row = blockIdx.x * 4 + wid;
    const ushort_t* hrow = hb + (size_t)row * NH;
    char* vrow = vb + (size_t)row * NH;
    const int yi = y[row];
    float d0 = 0, d1 = 0, d2 = 0, d3 = 0, d4 = 0;
#pragma unroll
    for (int it = 0; it < 2; ++it) {
        const int n0 = it * 512 + lane * 8;
        u16x8 hv = *(const u16x8*)(hrow + n0);
        float hh[8];
#pragma unroll
        for (int j = 0; j < 8; ++j) hh[j] = b2f(hv[j]);
#pragma unroll
        for (int c = 0; c < NC; ++c) {
            const float4 a = *(const float4*)&w2t[c][n0];
            const float4 b = *(const float4*)&w2t[c][n0 + 4];
            float d = hh[0] * a.x; d += hh[1] * a.y; d += hh[2] * a.z; d += hh[3] * a.w;
            d += hh[4] * b.x; d += hh[5] * b.y; d += hh[6] * b.z; d += hh[7] * b.w;
            if (c == 0) d0 += d; else if (c == 1) d1 += d; else if (c == 2) d2 += d;
            else if (c == 3) d3 += d; else d4 += d;
        }
        const float4 ya = *(const float4*)&w2t[yi][n0];
        const float4 yb = *(const float4*)&w2t[yi][n0 + 4];
        const float yw[8] = { ya.x, ya.y, ya.z, ya.w, yb.x, yb.y, yb.z, yb.w };
        union { char b[8]; long l; } ov;
#pragma unroll
        for (int j = 0; j < 8; ++j)
            ov.b[j] = f2i8((1.f - hh[j] * hh[j]) * yw[j], VS_I8);
        *(long*)(vrow + n0) = ov.l;
    }
#pragma unroll
    for (int off = 32; off; off >>= 1) {
        d0 += __shfl_xor(d0, off); d1 += __shfl_xor(d1, off); d2 += __shfl_xor(d2, off);
        d3 += __shfl_xor(d3, off); d4 += __shfl_xor(d4, off);
    }
    if (lane == 0) {
        float lg[NC] = { d0 + b2s[0], d1 + b2s[1], d2 + b2s[2], d3 + b2s[3], d4 + b2s[4] };
        float zy = lg[yi];
        float mse = 0.f, marg = 0.f;
        int amax = 0; float best = lg[0];
#pragma unroll
        for (int c = 0; c < NC; ++c) {
            float t = lg[c] - (c == yi ? 1.f : 0.f);
            mse += t * t;
            if (c != yi) marg += fmaxf(1.f - zy + lg[c], 0.f);
            if (lg[c] > best) { best = lg[c]; amax = c; }
        }
        rowstats[row] = make_float4(zy, mse, marg, (amax == yi) ? 1.f : 0.f);
    }
}

// ---------------- reductions ----------------
__global__ __launch_bounds__(256) void reduce_rows(const float4* __restrict__ rs,
                                                   const float* __restrict__ part,
                                                   int NT, float4* __restrict__ bsums) {
    const int tid = threadIdx.x;
    const int r = blockIdx.x * 256 + tid;
    float4 v = rs[r];
    float wl1 = 0.f;
    for (int t = 0; t < NT; ++t) wl1 += part[(size_t)t * NB + r];
    wl1 *= (1.0f / (VS_I8 * WS_I8));
    float R = wl1 * EPS_C / (fabsf(v.x) + 1e-8f);
    float4 s = make_float4(v.y, v.z, v.w, log1pf(R));
#pragma unroll
    for (int off = 32; off; off >>= 1) {
        s.x += __shfl_down(s.x, off); s.y += __shfl_down(s.y, off);
        s.z += __shfl_down(s.z, off); s.w += __shfl_down(s.w, off);
    }
    __shared__ float4 red[4];
    if ((tid & 63) == 0) red[tid >> 6] = s;
    __syncthreads();
    if (tid == 0) {
        float4 t = red[0];
        for (int i = 1; i < 4; ++i) { t.x += red[i].x; t.y += red[i].y; t.z += red[i].z; t.w += red[i].w; }
        bsums[blockIdx.x] = t;
    }
}

__global__ void final_combine(const float4* __restrict__ bsums, int nb, float* __restrict__ out) {
    const int l = threadIdx.x;
    float4 s = (l < nb) ? bsums[l] : make_float4(0.f, 0.f, 0.f, 0.f);
#pragma unroll
    for (int off = 32; off; off >>= 1) {
        s.x += __shfl_down(s.x, off); s.y += __shfl_down(s.y, off);
        s.z += __shfl_down(s.z, off); s.w += __shfl_down(s.w, off);
    }
    if (l == 0) {
        const float Bf = (float)NB;
        out[0] = s.x / (Bf * (float)NC) + (s.y / Bf + BETA * s.w / Bf) * (s.z / Bf);
    }
}

extern "C" void kernel_launch(void* const* d_in, const int* in_sizes, int n_in,
                              void* d_out, int out_size, void* d_ws, size_t ws_size,
                              hipStream_t stream) {
    const float* x  = (const float*)d_in[0];
    const int*   y  = (const int*)d_in[1];
    const float* W1 = (const float*)d_in[2];
    const float* b1 = (const float*)d_in[3];
    const float* W2 = (const float*)d_in[4];
    const float* b2 = (const float*)d_in[5];
    float* out = (float*)d_out;

    char* ws = (char*)d_ws;
    char*     W1Ti8 = (char*)(ws);                              // 2MB
    char*     W1i8  = (char*)(ws + (4ul << 20));                // 2MB
    char*     xi8   = (char*)(ws + (8ul << 20));                // 16MB
    ushort_t* hb    = (ushort_t*)(ws + (40ul << 20));           // 16MB
    char*     vi8   = (char*)(ws + (56ul << 20));               // 8MB
    float4*   rowstats = (float4*)(ws + (72ul << 20));          // 128KB
    float*    part = (float*)(ws + (72ul << 20) + (1ul << 20)); // 512KB
    float4*   bsums = (float4*)(ws + (74ul << 20));             // 512B

    // 1. merged prep: x -> i8(x*32); W1 -> i8 both orientations (one dispatch)
    prep_kernel<<<CVT_BLOCKS + TRANS_BLOCKS, 256, 0, stream>>>(x, xi8, W1, W1Ti8, W1i8);

    // 2. GEMM1 (i8, r16 proven): h = tanh(x @ W1 + b1)
    gi8<0><<<512, 256, 0, stream>>>(xi8, W1Ti8, b1, hb, nullptr);

    // 3. per-row: logits/mse/margin/zy/correct + v (i8, x800)
    rows_kernel<<<NB / 4, 256, 0, stream>>>(hb, y, W2, b2, vi8, rowstats);

    // 4. GEMM2 (i8, r16 proven): g = v @ W1^T, row |.| partials
    gi8<1><<<1024, 256, 0, stream>>>(vi8, W1i8, nullptr, nullptr, part);

    // 5. reductions
    reduce_rows<<<NB / 256, 256, 0, stream>>>(rowstats, part, NL / 128, bsums);
    final_combine<<<1, 64, 0, stream>>>(bsums, NB / 256, out);
}